// Round 9
// baseline (153.981 us; speedup 1.0000x reference)
//
#include <hip/hip_runtime.h>
#include <hip/hip_bf16.h>

#define D 64
#define CAP 32      // slots per node = one 64B line (row == line)
#define OVF_CAP 16384
#define NSHARD 8    // dst shards, bound to XCDs via blockIdx&7 heuristic
#define TROWS 32    // x rows staged per block in the LDS MLP (r27: 64->32 for 2x blocks)

// Probe ledger (all us):
//  r19: M(mlp)=25.2  A+X=22.2  V(harness fixed)=109.7
//  r22: LDS-staged MLP 10.0 vs broadcast-load 24 (2.4x) -> ADOPTED
//  r23: A(sharded append)=17.3  X(gather)=2.2
//  r24: UNSHARDED append REGRESSED (A=28.6; cross-XCD line dirtying) -> NSHARD=8 stays.
//  r26: unroll-4 atomic ILP REGRESSED (A=22.3 timed, ~45 rocprof). Latency-round
//       theory REFUTED: ILP+TLP don't move it -> append is THROUGHPUT-bound at
//       the coherence point (~19 atomics/cyc chip-wide). 800k return-atomics is
//       the algorithm's floor; LDS-histogram alternatives cost more than they save.
//  r27 (this round): append REVERTED to r23 verbatim (A=17.3 measured).
//       MLP levers: TROWS 32 (1563 blocks, ~6/CU -> 2x resident waves) +
//       4 rows/iter (4 indep FMA chains). Per-row FMA order unchanged ->
//       bit-identical numerics. Predict M 10 -> 6-7.5, total 135-138.

__device__ __forceinline__ float bf2f(unsigned short u) {
    return __uint_as_float((unsigned int)u << 16);
}
__device__ __forceinline__ unsigned short f2bf(float f) {
    unsigned int u = __float_as_uint(f);
    unsigned int r = (u + 0x7fffu + ((u >> 16) & 1u)) >> 16;   // RNE
    return (unsigned short)r;
}

// ---------- Kernel 1: LDS-staged node MLP (r22 structure, r27 tuning) ----------
// m[n][:] = bf16(relu(x @ W + b)); also zeros cnt/ovf_cnt.
__global__ __launch_bounds__(256) void node_mlp_lds_kernel(
    const float* __restrict__ x, const float* __restrict__ W,
    const float* __restrict__ b, unsigned short* __restrict__ m,
    int* __restrict__ cnt, int* __restrict__ ovf_cnt, int n_nodes) {
    __shared__ float tile[TROWS][68];   // 68-float stride: 16B-aligned rows
    for (int i = blockIdx.x * blockDim.x + threadIdx.x; i < n_nodes;
         i += gridDim.x * blockDim.x) cnt[i] = 0;
    if (blockIdx.x == 0 && threadIdx.x == 0) *ovf_cnt = 0;

    const int lane = threadIdx.x & 63;
    const int wv = threadIdx.x >> 6;        // wave-in-block 0..3
    float w[D];
    #pragma unroll
    for (int k = 0; k < D; ++k) w[k] = W[k * D + lane];
    const float bias = b[lane];

    for (int t0 = blockIdx.x * TROWS; t0 < n_nodes; t0 += gridDim.x * TROWS) {
        const int nr = min(TROWS, n_nodes - t0);
        {   // stage: thread t covers row t>>3, 8-float segment t&7 (32B)
            const int r = threadIdx.x >> 3, sg = threadIdx.x & 7;
            if (r < nr) {
                const float4* s4 = (const float4*)(x + (size_t)(t0 + r) * D + sg * 8);
                float4 a0 = s4[0], a1 = s4[1];
                float* dl = &tile[r][sg * 8];
                *(float4*)(dl + 0) = a0;
                *(float4*)(dl + 4) = a1;
            }
        }
        __syncthreads();
        // each wave owns 8 rows; process 4 at a time (4 independent FMA chains)
        const int rend = min(wv * 8 + 8, nr);
        for (int rr = wv * 8; rr < rend; rr += 4) {
            const int r0 = rr;
            const int r1 = min(rr + 1, rend - 1);
            const int r2 = min(rr + 2, rend - 1);
            const int r3 = min(rr + 3, rend - 1);
            float acc0 = bias, acc1 = bias, acc2 = bias, acc3 = bias;
            #pragma unroll
            for (int kk = 0; kk < D / 4; ++kk) {
                float4 a = *(const float4*)&tile[r0][4 * kk];  // uniform -> LDS broadcast
                float4 c = *(const float4*)&tile[r1][4 * kk];
                float4 e = *(const float4*)&tile[r2][4 * kk];
                float4 g = *(const float4*)&tile[r3][4 * kk];
                acc0 = fmaf(a.x, w[4 * kk + 0], acc0);
                acc1 = fmaf(c.x, w[4 * kk + 0], acc1);
                acc2 = fmaf(e.x, w[4 * kk + 0], acc2);
                acc3 = fmaf(g.x, w[4 * kk + 0], acc3);
                acc0 = fmaf(a.y, w[4 * kk + 1], acc0);
                acc1 = fmaf(c.y, w[4 * kk + 1], acc1);
                acc2 = fmaf(e.y, w[4 * kk + 1], acc2);
                acc3 = fmaf(g.y, w[4 * kk + 1], acc3);
                acc0 = fmaf(a.z, w[4 * kk + 2], acc0);
                acc1 = fmaf(c.z, w[4 * kk + 2], acc1);
                acc2 = fmaf(e.z, w[4 * kk + 2], acc2);
                acc3 = fmaf(g.z, w[4 * kk + 2], acc3);
                acc0 = fmaf(a.w, w[4 * kk + 3], acc0);
                acc1 = fmaf(c.w, w[4 * kk + 3], acc1);
                acc2 = fmaf(e.w, w[4 * kk + 3], acc2);
                acc3 = fmaf(g.w, w[4 * kk + 3], acc3);
            }
            m[(size_t)(t0 + r0) * D + lane] = f2bf(fmaxf(acc0, 0.0f));
            if (rr + 1 < rend) m[(size_t)(t0 + r1) * D + lane] = f2bf(fmaxf(acc1, 0.0f));
            if (rr + 2 < rend) m[(size_t)(t0 + r2) * D + lane] = f2bf(fmaxf(acc2, 0.0f));
            if (rr + 3 < rend) m[(size_t)(t0 + r3) * D + lane] = f2bf(fmaxf(acc3, 0.0f));
        }
        __syncthreads();                 // tile reuse guard (grid-stride safety)
    }
}

// ---------- Kernel 2: XCD-sharded append (r23 form, reverted verbatim) ----------
// Block group k (blockIdx&7==k) handles only dst with (d&7)==k; co-resident
// blocks share an XCD under round-robin dispatch, so each slot line is
// written by one L2 and merges into a single writeback (r12 win, r24-confirmed).
// A=17.3us is the structural floor: bound by memory-side atomic throughput
// (~19/cyc chip-wide); ILP (r26) and unsharding (r24) both regressed.
__global__ __launch_bounds__(256) void append_kernel(
    const int* __restrict__ src, const int* __restrict__ dst,
    int* __restrict__ cnt, unsigned short* __restrict__ slots,
    int* __restrict__ ovf_cnt, unsigned int* __restrict__ ovf,
    int n_edges, int blocks_per_shard) {
    const int shard = blockIdx.x & (NSHARD - 1);
    const int p = blockIdx.x >> 3;          // rank within shard group
    const int chunk = (n_edges + blocks_per_shard - 1) / blocks_per_shard;
    const int beg = p * chunk;
    const int end = min(beg + chunk, n_edges);

    for (int e = beg + (int)threadIdx.x; e < end; e += 256) {
        int d = dst[e];                      // coalesced; L3-served (8x redundant)
        if ((d & (NSHARD - 1)) != shard) continue;
        int s = src[e];
        int pos = atomicAdd(&cnt[d], 1);     // memory-side atomic
        if (pos < CAP) {
            slots[(size_t)d * CAP + pos] = (unsigned short)s;
        } else {                             // ~4 nodes expected (P(deg>32)~8e-5)
            int op = atomicAdd(ovf_cnt, 1);
            if (op < OVF_CAP)
                ovf[op] = ((unsigned int)d << 16) | (unsigned int)s;
        }
    }
}

// ---------- Kernel 3: gather — one wave/node, fully scalar addressing (r15 win) ----------
__global__ __launch_bounds__(256) void gather_kernel(
    const unsigned short* __restrict__ slots, const int* __restrict__ cnt,
    const unsigned short* __restrict__ m,
    const int* __restrict__ ovf_cnt, const unsigned int* __restrict__ ovf,
    float* __restrict__ out, int n_nodes) {
    const int grp = blockIdx.x >> 3;          // 8-block group covers 32 nodes
    const int xcd = blockIdx.x & 7;
    int node = grp * 32 + ((threadIdx.x >> 6) << 3) + xcd;  // node&7 == blockIdx&7
    if (node >= n_nodes) return;              // wave-uniform branch
    node = __builtin_amdgcn_readfirstlane(node);

    const int lane = threadIdx.x & 63;

    const int c = cnt[node];                  // scalar load
    const int cc = min(c, CAP);
    const unsigned int* __restrict__ row =
        (const unsigned int*)(slots + (size_t)node * CAP);  // scalar base

    float acc = 0.0f;
    int k = 0;
    for (; k + 16 <= cc; k += 16) {
        unsigned int p[8];
        #pragma unroll
        for (int i = 0; i < 8; ++i) p[i] = row[(k >> 1) + i];  // s_load x8
        float v[16];
        #pragma unroll
        for (int i = 0; i < 8; ++i) {         // 16 saddr loads in flight
            const unsigned short* ba = m + (size_t)(p[i] & 0xFFFFu) * D; // SGPR base
            const unsigned short* bb = m + (size_t)(p[i] >> 16) * D;     // SGPR base
            v[2 * i + 0] = bf2f(ba[lane]);
            v[2 * i + 1] = bf2f(bb[lane]);
        }
        float t0 = ((v[0] + v[1]) + (v[2] + v[3])) + ((v[4] + v[5]) + (v[6] + v[7]));
        float t1 = ((v[8] + v[9]) + (v[10] + v[11])) + ((v[12] + v[13]) + (v[14] + v[15]));
        acc += t0 + t1;
    }
    for (; k + 4 <= cc; k += 4) {
        unsigned int p0 = row[(k >> 1) + 0];
        unsigned int p1 = row[(k >> 1) + 1];
        const unsigned short* b0 = m + (size_t)(p0 & 0xFFFFu) * D;
        const unsigned short* b1 = m + (size_t)(p0 >> 16) * D;
        const unsigned short* b2 = m + (size_t)(p1 & 0xFFFFu) * D;
        const unsigned short* b3 = m + (size_t)(p1 >> 16) * D;
        float v0 = bf2f(b0[lane]);
        float v1 = bf2f(b1[lane]);
        float v2 = bf2f(b2[lane]);
        float v3 = bf2f(b3[lane]);
        acc += (v0 + v1) + (v2 + v3);
    }
    for (; k < cc; ++k) {
        unsigned int p = row[k >> 1];
        unsigned int s = (k & 1) ? (p >> 16) : (p & 0xFFFFu);
        acc += bf2f(m[(size_t)s * D + lane]);
    }
    if (c > CAP) {                            // rare: scan tiny ovf list (uniform)
        int oc = min(*ovf_cnt, OVF_CAP);
        for (int i = 0; i < oc; ++i) {
            unsigned int e = ovf[i];
            if ((int)(e >> 16) == node)
                acc += bf2f(m[(size_t)(e & 0xFFFFu) * D + lane]);
        }
    }
    out[(size_t)node * D + lane] = acc;       // fully coalesced 256B/wave
}

// ---------- Fallback: atomic scatter (unified m) ----------
__global__ __launch_bounds__(256) void edge_scatter_kernel(
    const int* __restrict__ src, const int* __restrict__ dst,
    const unsigned short* __restrict__ m, float* __restrict__ out, int n_edges) {
    long long t = (long long)blockIdx.x * blockDim.x + threadIdx.x;
    int e = (int)(t >> 4);
    if (e >= n_edges) return;
    int c = (int)(t & 15) << 2;
    int s = src[e];
    int d = dst[e];
    const ushort4 v = *(const ushort4*)(m + (size_t)s * D + c);
    float* o = out + (size_t)d * D + c;
    atomicAdd(o + 0, bf2f(v.x));
    atomicAdd(o + 1, bf2f(v.y));
    atomicAdd(o + 2, bf2f(v.z));
    atomicAdd(o + 3, bf2f(v.w));
}

static inline size_t align_up(size_t v, size_t a) { return (v + a - 1) & ~(a - 1); }

extern "C" void kernel_launch(void* const* d_in, const int* in_sizes, int n_in,
                              void* d_out, int out_size, void* d_ws, size_t ws_size,
                              hipStream_t stream) {
    const float* x = (const float*)d_in[0];
    const int* edge_index = (const int*)d_in[1];   // int32 per harness contract
    const float* W = (const float*)d_in[2];
    const float* b = (const float*)d_in[3];
    float* out = (float*)d_out;

    const int n_nodes = in_sizes[0] / D;        // 50000
    const int n_edges = in_sizes[1] / 2;        // 800000
    const int* src = edge_index;                // row 0 (j, gather)
    const int* dst = edge_index + n_edges;      // row 1 (i, scatter)

    // Workspace layout (~10 MB total)
    size_t off = 0;
    unsigned short* m = (unsigned short*)((char*)d_ws + off);
    off = align_up(off + (size_t)n_nodes * D * sizeof(unsigned short), 256);
    int* cnt = (int*)((char*)d_ws + off);
    off = align_up(off + (size_t)n_nodes * sizeof(int), 256);
    unsigned short* slots = (unsigned short*)((char*)d_ws + off);
    off = align_up(off + (size_t)n_nodes * CAP * sizeof(unsigned short), 256);
    int* ovf_cnt = (int*)((char*)d_ws + off);
    off = align_up(off + sizeof(int), 256);
    unsigned int* ovf = (unsigned int*)((char*)d_ws + off);
    off = align_up(off + (size_t)OVF_CAP * sizeof(unsigned int), 256);
    const size_t needed = off;

    // MLP: LDS-staged, TROWS=32 -> 1563 blocks (~6/CU resident)
    const int mlp_blocks = (n_nodes + TROWS - 1) / TROWS;
    node_mlp_lds_kernel<<<mlp_blocks, 256, 0, stream>>>(x, W, b, m, cnt, ovf_cnt, n_nodes);

    if (ws_size >= needed && n_nodes <= 65536) {
        const int blocks_per_shard = 320;           // 2560 blocks (r16 best)
        append_kernel<<<blocks_per_shard * NSHARD, 256, 0, stream>>>(
            src, dst, cnt, slots, ovf_cnt, ovf, n_edges, blocks_per_shard);
        const int ngroups = (n_nodes + 31) / 32;    // 8 blocks per 32-node group
        gather_kernel<<<ngroups * 8, 256, 0, stream>>>(
            slots, cnt, m, ovf_cnt, ovf, out, n_nodes);
    } else {
        hipMemsetAsync(d_out, 0, (size_t)out_size * sizeof(float), stream);
        long long total_threads = (long long)n_edges * 16;
        int scat_blocks = (int)((total_threads + 255) / 256);
        edge_scatter_kernel<<<scat_blocks, 256, 0, stream>>>(src, dst, m, out, n_edges);
    }
}

// Round 10
// 139.631 us; speedup vs baseline: 1.1028x; 1.1028x over previous
//
#include <hip/hip_runtime.h>
#include <hip/hip_bf16.h>

#define D 64
#define CAP 32      // slots per node = one 64B line (row == line)
#define OVF_CAP 16384
#define NSHARD 8    // dst shards, bound to XCDs via blockIdx&7 heuristic
#define TROWS 64    // x rows staged per block (r22 winner; r27's 32 regressed)

// Probe ledger (all us):
//  r19: M(mlp)=25.2  A+X=22.2  V(harness fixed)=109.7
//  r22: LDS-staged MLP M=10.0 (TROWS=64, 2-row) vs broadcast-load 24 -> ADOPTED
//  r23: A(sharded append)=17.3  X(gather)=2.2
//  r24: UNSHARDED append REGRESSED (A=28.6; cross-XCD line dirtying) -> NSHARD=8 final.
//  r26: append atomic-ILP unroll-4 REGRESSED (A=22.3) -> append is THROUGHPUT-
//       bound at the coherence point (~19 atomics/cyc chip-wide); r23 form = floor.
//  r27: MLP TROWS=32 + 4-row unroll REGRESSED (M~24.8; suspect VGPR>64 occupancy
//       cliff -- r22 version measured VGPR_Count=48 -- and/or 32B/thread stage).
//  r28 (this round): assemble the measured-best combination, all reverts:
//       r22 MLP + r23 append + r15 gather. Predict total 139-141.
//       Controllables floor reached on A (2 refutations) and X; V~110 is harness.

__device__ __forceinline__ float bf2f(unsigned short u) {
    return __uint_as_float((unsigned int)u << 16);
}
__device__ __forceinline__ unsigned short f2bf(float f) {
    unsigned int u = __float_as_uint(f);
    unsigned int r = (u + 0x7fffu + ((u >> 16) & 1u)) >> 16;   // RNE
    return (unsigned short)r;
}

// ---------- Kernel 1: LDS-staged node MLP (r22 winner, verbatim) ----------
// m[n][:] = bf16(relu(x @ W + b)); also zeros cnt/ovf_cnt.
__global__ __launch_bounds__(256) void node_mlp_lds_kernel(
    const float* __restrict__ x, const float* __restrict__ W,
    const float* __restrict__ b, unsigned short* __restrict__ m,
    int* __restrict__ cnt, int* __restrict__ ovf_cnt, int n_nodes) {
    __shared__ float tile[TROWS][68];   // 68-float stride: 16B-aligned rows
    for (int i = blockIdx.x * blockDim.x + threadIdx.x; i < n_nodes;
         i += gridDim.x * blockDim.x) cnt[i] = 0;
    if (blockIdx.x == 0 && threadIdx.x == 0) *ovf_cnt = 0;

    const int lane = threadIdx.x & 63;
    const int wv = threadIdx.x >> 6;        // wave-in-block 0..3
    float w[D];
    #pragma unroll
    for (int k = 0; k < D; ++k) w[k] = W[k * D + lane];
    const float bias = b[lane];

    for (int t0 = blockIdx.x * TROWS; t0 < n_nodes; t0 += gridDim.x * TROWS) {
        const int nr = min(TROWS, n_nodes - t0);
        {   // stage: thread t covers row t>>2, 16-float segment t&3 (64B)
            const int r = threadIdx.x >> 2, sg = threadIdx.x & 3;
            if (r < nr) {
                const float4* s4 = (const float4*)(x + (size_t)(t0 + r) * D + sg * 16);
                float4 a0 = s4[0], a1 = s4[1], a2 = s4[2], a3 = s4[3];
                float* dl = &tile[r][sg * 16];
                *(float4*)(dl + 0)  = a0;
                *(float4*)(dl + 4)  = a1;
                *(float4*)(dl + 8)  = a2;
                *(float4*)(dl + 12) = a3;
            }
        }
        __syncthreads();
        const int rend = min(wv * 16 + 16, nr);
        for (int rr = wv * 16; rr < rend; rr += 2) {
            const int r0 = rr;
            const int r1 = (rr + 1 < rend) ? rr + 1 : rr;
            float acc0 = bias, acc1 = bias;
            #pragma unroll
            for (int kk = 0; kk < D / 4; ++kk) {
                float4 a = *(const float4*)&tile[r0][4 * kk];  // uniform -> LDS broadcast
                float4 c = *(const float4*)&tile[r1][4 * kk];
                acc0 = fmaf(a.x, w[4 * kk + 0], acc0);
                acc1 = fmaf(c.x, w[4 * kk + 0], acc1);
                acc0 = fmaf(a.y, w[4 * kk + 1], acc0);
                acc1 = fmaf(c.y, w[4 * kk + 1], acc1);
                acc0 = fmaf(a.z, w[4 * kk + 2], acc0);
                acc1 = fmaf(c.z, w[4 * kk + 2], acc1);
                acc0 = fmaf(a.w, w[4 * kk + 3], acc0);
                acc1 = fmaf(c.w, w[4 * kk + 3], acc1);
            }
            m[(size_t)(t0 + r0) * D + lane] = f2bf(fmaxf(acc0, 0.0f));
            if (r1 > r0)
                m[(size_t)(t0 + r1) * D + lane] = f2bf(fmaxf(acc1, 0.0f));
        }
        __syncthreads();                 // tile reuse guard (grid-stride safety)
    }
}

// ---------- Kernel 2: XCD-sharded append (r23 form; measured floor A=17.3) ----------
// Block group k (blockIdx&7==k) handles only dst with (d&7)==k; co-resident
// blocks share an XCD under round-robin dispatch, so each slot line is
// written by one L2 and merges into a single writeback (r12 win, r24-confirmed).
// Bound by memory-side atomic throughput; ILP (r26) and unsharding (r24) regressed.
__global__ __launch_bounds__(256) void append_kernel(
    const int* __restrict__ src, const int* __restrict__ dst,
    int* __restrict__ cnt, unsigned short* __restrict__ slots,
    int* __restrict__ ovf_cnt, unsigned int* __restrict__ ovf,
    int n_edges, int blocks_per_shard) {
    const int shard = blockIdx.x & (NSHARD - 1);
    const int p = blockIdx.x >> 3;          // rank within shard group
    const int chunk = (n_edges + blocks_per_shard - 1) / blocks_per_shard;
    const int beg = p * chunk;
    const int end = min(beg + chunk, n_edges);

    for (int e = beg + (int)threadIdx.x; e < end; e += 256) {
        int d = dst[e];                      // coalesced; L3-served (8x redundant)
        if ((d & (NSHARD - 1)) != shard) continue;
        int s = src[e];
        int pos = atomicAdd(&cnt[d], 1);     // memory-side atomic
        if (pos < CAP) {
            slots[(size_t)d * CAP + pos] = (unsigned short)s;
        } else {                             // ~4 nodes expected (P(deg>32)~8e-5)
            int op = atomicAdd(ovf_cnt, 1);
            if (op < OVF_CAP)
                ovf[op] = ((unsigned int)d << 16) | (unsigned int)s;
        }
    }
}

// ---------- Kernel 3: gather — one wave/node, fully scalar addressing (r15 win) ----------
__global__ __launch_bounds__(256) void gather_kernel(
    const unsigned short* __restrict__ slots, const int* __restrict__ cnt,
    const unsigned short* __restrict__ m,
    const int* __restrict__ ovf_cnt, const unsigned int* __restrict__ ovf,
    float* __restrict__ out, int n_nodes) {
    const int grp = blockIdx.x >> 3;          // 8-block group covers 32 nodes
    const int xcd = blockIdx.x & 7;
    int node = grp * 32 + ((threadIdx.x >> 6) << 3) + xcd;  // node&7 == blockIdx&7
    if (node >= n_nodes) return;              // wave-uniform branch
    node = __builtin_amdgcn_readfirstlane(node);

    const int lane = threadIdx.x & 63;

    const int c = cnt[node];                  // scalar load
    const int cc = min(c, CAP);
    const unsigned int* __restrict__ row =
        (const unsigned int*)(slots + (size_t)node * CAP);  // scalar base

    float acc = 0.0f;
    int k = 0;
    for (; k + 16 <= cc; k += 16) {
        unsigned int p[8];
        #pragma unroll
        for (int i = 0; i < 8; ++i) p[i] = row[(k >> 1) + i];  // s_load x8
        float v[16];
        #pragma unroll
        for (int i = 0; i < 8; ++i) {         // 16 saddr loads in flight
            const unsigned short* ba = m + (size_t)(p[i] & 0xFFFFu) * D; // SGPR base
            const unsigned short* bb = m + (size_t)(p[i] >> 16) * D;     // SGPR base
            v[2 * i + 0] = bf2f(ba[lane]);
            v[2 * i + 1] = bf2f(bb[lane]);
        }
        float t0 = ((v[0] + v[1]) + (v[2] + v[3])) + ((v[4] + v[5]) + (v[6] + v[7]));
        float t1 = ((v[8] + v[9]) + (v[10] + v[11])) + ((v[12] + v[13]) + (v[14] + v[15]));
        acc += t0 + t1;
    }
    for (; k + 4 <= cc; k += 4) {
        unsigned int p0 = row[(k >> 1) + 0];
        unsigned int p1 = row[(k >> 1) + 1];
        const unsigned short* b0 = m + (size_t)(p0 & 0xFFFFu) * D;
        const unsigned short* b1 = m + (size_t)(p0 >> 16) * D;
        const unsigned short* b2 = m + (size_t)(p1 & 0xFFFFu) * D;
        const unsigned short* b3 = m + (size_t)(p1 >> 16) * D;
        float v0 = bf2f(b0[lane]);
        float v1 = bf2f(b1[lane]);
        float v2 = bf2f(b2[lane]);
        float v3 = bf2f(b3[lane]);
        acc += (v0 + v1) + (v2 + v3);
    }
    for (; k < cc; ++k) {
        unsigned int p = row[k >> 1];
        unsigned int s = (k & 1) ? (p >> 16) : (p & 0xFFFFu);
        acc += bf2f(m[(size_t)s * D + lane]);
    }
    if (c > CAP) {                            // rare: scan tiny ovf list (uniform)
        int oc = min(*ovf_cnt, OVF_CAP);
        for (int i = 0; i < oc; ++i) {
            unsigned int e = ovf[i];
            if ((int)(e >> 16) == node)
                acc += bf2f(m[(size_t)(e & 0xFFFFu) * D + lane]);
        }
    }
    out[(size_t)node * D + lane] = acc;       // fully coalesced 256B/wave
}

// ---------- Fallback: atomic scatter (unified m) ----------
__global__ __launch_bounds__(256) void edge_scatter_kernel(
    const int* __restrict__ src, const int* __restrict__ dst,
    const unsigned short* __restrict__ m, float* __restrict__ out, int n_edges) {
    long long t = (long long)blockIdx.x * blockDim.x + threadIdx.x;
    int e = (int)(t >> 4);
    if (e >= n_edges) return;
    int c = (int)(t & 15) << 2;
    int s = src[e];
    int d = dst[e];
    const ushort4 v = *(const ushort4*)(m + (size_t)s * D + c);
    float* o = out + (size_t)d * D + c;
    atomicAdd(o + 0, bf2f(v.x));
    atomicAdd(o + 1, bf2f(v.y));
    atomicAdd(o + 2, bf2f(v.z));
    atomicAdd(o + 3, bf2f(v.w));
}

static inline size_t align_up(size_t v, size_t a) { return (v + a - 1) & ~(a - 1); }

extern "C" void kernel_launch(void* const* d_in, const int* in_sizes, int n_in,
                              void* d_out, int out_size, void* d_ws, size_t ws_size,
                              hipStream_t stream) {
    const float* x = (const float*)d_in[0];
    const int* edge_index = (const int*)d_in[1];   // int32 per harness contract
    const float* W = (const float*)d_in[2];
    const float* b = (const float*)d_in[3];
    float* out = (float*)d_out;

    const int n_nodes = in_sizes[0] / D;        // 50000
    const int n_edges = in_sizes[1] / 2;        // 800000
    const int* src = edge_index;                // row 0 (j, gather)
    const int* dst = edge_index + n_edges;      // row 1 (i, scatter)

    // Workspace layout (~10 MB total)
    size_t off = 0;
    unsigned short* m = (unsigned short*)((char*)d_ws + off);
    off = align_up(off + (size_t)n_nodes * D * sizeof(unsigned short), 256);
    int* cnt = (int*)((char*)d_ws + off);
    off = align_up(off + (size_t)n_nodes * sizeof(int), 256);
    unsigned short* slots = (unsigned short*)((char*)d_ws + off);
    off = align_up(off + (size_t)n_nodes * CAP * sizeof(unsigned short), 256);
    int* ovf_cnt = (int*)((char*)d_ws + off);
    off = align_up(off + sizeof(int), 256);
    unsigned int* ovf = (unsigned int*)((char*)d_ws + off);
    off = align_up(off + (size_t)OVF_CAP * sizeof(unsigned int), 256);
    const size_t needed = off;

    // MLP: LDS-staged form (r22 winner), 782 blocks x 256
    const int mlp_blocks = (n_nodes + TROWS - 1) / TROWS;
    node_mlp_lds_kernel<<<mlp_blocks, 256, 0, stream>>>(x, W, b, m, cnt, ovf_cnt, n_nodes);

    if (ws_size >= needed && n_nodes <= 65536) {
        const int blocks_per_shard = 320;           // 2560 blocks (r16 best)
        append_kernel<<<blocks_per_shard * NSHARD, 256, 0, stream>>>(
            src, dst, cnt, slots, ovf_cnt, ovf, n_edges, blocks_per_shard);
        const int ngroups = (n_nodes + 31) / 32;    // 8 blocks per 32-node group
        gather_kernel<<<ngroups * 8, 256, 0, stream>>>(
            slots, cnt, m, ovf_cnt, ovf, out, n_nodes);
    } else {
        hipMemsetAsync(d_out, 0, (size_t)out_size * sizeof(float), stream);
        long long total_threads = (long long)n_edges * 16;
        int scat_blocks = (int)((total_threads + 255) / 256);
        edge_scatter_kernel<<<scat_blocks, 256, 0, stream>>>(src, dst, m, out, n_edges);
    }
}